// Round 14
// baseline (4181983.887 us; speedup 1.0000x reference)
//
#include <hip/hip_runtime.h>

// RecurrentNEFLayer on MI355X — persistent-kernel scan.
// r14 = r11 (champion, 1505us) + XCD-LOCAL communication when verified safe.
// 128 blocks = 16 batch-groups (16 rows) x 8 neuron-groups (256 neurons);
// group g = blocks {g + 16*p}, all ≡ g (mod 8) -> same XCD under the measured
// round-robin dispatch map. Each block reads HW_REG_XCC_ID and the group
// verifies co-location at startup (hidden under weight staging):
//   verified  -> L2-scope comm: global_atomic_add_f32 (no sc1) for the s
//               reduction, sc0 loads for poll/S-read, sc0 stores for zeroing.
//               RTT ~200cy vs ~700cy at the MALL.
//   not       -> byte-identical r11 MALL path (agent-scope ops). Worst case
//               equals the current best kernel; both paths same arithmetic.
// Protocol/rotation/flags unchanged from r11.

constexpr int CB   = 256;
constexpr int CT   = 512;
constexpr int DIN  = 128;
constexpr int DST  = 128;
constexpr int DOUT = 64;
constexpr int DAUG = 256;

constexpr int NBG = 16;     // batch groups
constexpr int NNG = 8;      // neuron groups (blocks per barrier group)
constexpr int BT  = 16;     // batch rows per group
constexpr int NT  = 256;    // neurons per block

constexpr int EPAD = 264;   // 256 + 8 bf16 pad
constexpr int APAD = 264;

using f32x4  = __attribute__((ext_vector_type(4))) float;
using bf16x8 = __attribute__((ext_vector_type(8))) short;

template<bool B> struct BoolC { static constexpr bool value = B; };

__device__ __forceinline__ short f2b(float x) {   // f32 -> bf16 RNE
  unsigned u = __builtin_bit_cast(unsigned, x);
  u += 0x7fffu + ((u >> 16) & 1u);
  return (short)(u >> 16);
}
__device__ __forceinline__ short4 f2b4(float4 v) {
  return make_short4(f2b(v.x), f2b(v.y), f2b(v.z), f2b(v.w));
}

// ---- L2-scope (XCD-local) memory ops: no sc1 -> RMW/read at local L2 ----
__device__ __forceinline__ void addF32_l2(float* p, float v) {
  asm volatile("global_atomic_add_f32 %0, %1, off" :: "v"(p), "v"(v) : "memory");
}
__device__ __forceinline__ void addU32_l2(unsigned* p, unsigned v) {
  asm volatile("global_atomic_add %0, %1, off" :: "v"(p), "v"(v) : "memory");
}
__device__ __forceinline__ unsigned loadU32_l2(const unsigned* p) {
  unsigned r;
  asm volatile("global_load_dword %0, %1, off sc0\n\ts_waitcnt vmcnt(0)"
               : "=v"(r) : "v"(p) : "memory");
  return r;
}
__device__ __forceinline__ void storeF32_l2(float* p, float v) {
  asm volatile("global_store_dword %0, %1, off sc0" :: "v"(p), "v"(v) : "memory");
}

__global__ void nef_init(float* Sbuf, unsigned int* ctrs, unsigned int* xtab,
                         float* out) {
  int idx = blockIdx.x * blockDim.x + threadIdx.x;
  int stride = gridDim.x * blockDim.x;
  for (int i = idx; i < 4 * CB * DST; i += stride) Sbuf[i] = 0.f;
  for (int i = idx; i < CB * DOUT; i += stride) out[i] = 0.f;
  if (idx < 16 * 64) ctrs[idx] = 0u;
  if (idx < 128) xtab[idx] = 0u;
}

__global__ void __launch_bounds__(256) nef_main(
    const float* __restrict__ seq,  const float* __restrict__ enc,
    const float* __restrict__ gainp,const float* __restrict__ biasp,
    const float* __restrict__ sdec, const float* __restrict__ dec,
    float* __restrict__ out, float* __restrict__ Sbuf,
    unsigned int* ctrs, unsigned int* xtab)
{
  __shared__ short E_lds[NT][EPAD];     // encoders [n][k_aug]   135.2 KB
  __shared__ short X_lds[BT][EPAD];     // [u_t|s_t][b][k_aug]     8.4 KB
  __shared__ short A_lds[BT][APAD];     // activations [b][n]      8.4 KB
  __shared__ float gain_lds[NT];
  __shared__ float bias_lds[NT];
  __shared__ int   fast_sh;

  const int tid  = threadIdx.x;
  const int bg   = blockIdx.x & 15;
  const int ng   = blockIdx.x >> 4;
  const int b0   = bg * BT;
  const int n0   = ng * NT;
  const int wave = tid >> 6;
  const int lane = tid & 63;
  const int l15  = lane & 15;
  const int lhi  = lane >> 4;
  const int kbase = lhi * 8;

  // ---- publish this block's XCD id (one-time, agent scope) ----
  unsigned xcc;
  asm volatile("s_getreg_b32 %0, hwreg(HW_REG_XCC_ID)" : "=s"(xcc));
  xcc &= 0xfu;
  if (tid == 0)
    __hip_atomic_store(&xtab[blockIdx.x], xcc + 1u,
                       __ATOMIC_RELAXED, __HIP_MEMORY_SCOPE_AGENT);

  // ---- one-time: stage encoders into LDS (bf16) ----
  for (int i = 0; i < 64; ++i) {
    int fidx = i * 256 + tid;
    int row = fidx >> 6, c4 = fidx & 63;
    const float4 v = *(const float4*)(enc + (size_t)(n0 + row) * DAUG + (c4 << 2));
    *(short4*)&E_lds[row][c4 << 2] = f2b4(v);
  }
  gain_lds[tid] = gainp[n0 + tid];
  bias_lds[tid] = biasp[n0 + tid];

  // ---- one-time: state_decoders^T fragments into registers ----
  bf16x8 sdt0[8], sdt1[8];
#pragma unroll
  for (int kk = 0; kk < 8; ++kk) {
    bf16x8 f0, f1;
    const int dA = wave * 32 + l15, dB = dA + 16;
#pragma unroll
    for (int j = 0; j < 8; ++j) {
      const size_t nrow = (size_t)(n0 + kk * 32 + kbase + j) * DST;
      f0[j] = f2b(sdec[nrow + dA]);
      f1[j] = f2b(sdec[nrow + dB]);
    }
    sdt0[kk] = f0; sdt1[kk] = f1;
  }

  unsigned int* ctr = ctrs + bg * 64;
  const int nsub = wave * 64;

  // ---- prologue: u_0 -> X, prefetch u_1 ----
  float4 pu[2];
#pragma unroll
  for (int i = 0; i < 2; ++i) {
    int fidx = i * 256 + tid;
    int row = fidx >> 5, c4 = fidx & 31;
    pu[i] = *(const float4*)(seq + ((size_t)(b0 + row) * CT + 0) * DIN + (c4 << 2));
  }
#pragma unroll
  for (int i = 0; i < 2; ++i) {
    int fidx = i * 256 + tid;
    int row = fidx >> 5, c4 = fidx & 31;
    *(short4*)&X_lds[row][c4 << 2] = f2b4(pu[i]);
    pu[i] = *(const float4*)(seq + ((size_t)(b0 + row) * CT + 1) * DIN + (c4 << 2));
  }

  // ---- verify all 8 group members share this XCD (hidden under staging) ----
  if (tid == 0) {
    bool ok = true;
    for (int p = 0; p < NNG; ++p) {
      unsigned v = 0, guard = 0;
      do {
        v = __hip_atomic_load(&xtab[bg + 16 * p],
                              __ATOMIC_RELAXED, __HIP_MEMORY_SCOPE_AGENT);
        if (v) break;
        __builtin_amdgcn_s_sleep(1);
      } while (++guard < 2000000u);
      ok = ok && (v == xcc + 1u);
    }
    fast_sh = ok ? 1 : 0;
  }
  __syncthreads();   // weights + u_0 + fast_sh
  const bool fast = (fast_sh != 0);

  auto body = [&](auto fc) {
    constexpr bool FAST = decltype(fc)::value;
    for (int t = 0; t < CT; ++t) {
      // ---- zero S[(t+2)&3] (drained before this step's flag by barrier (2);
      // readers of that buffer finished at t-2 since we passed poll(t-1)) ----
      {
        float* zp = Sbuf + ((t + 2) & 3) * (CB * DST) + b0 * DST + ng * 256 + tid;
        if constexpr (FAST) storeF32_l2(zp, 0.f);
        else __hip_atomic_store(zp, 0.f, __ATOMIC_RELAXED, __HIP_MEMORY_SCOPE_AGENT);
      }

      // ---- GEMM A u-half (kk 0..3): s-independent pre-poll work ----
      f32x4 acc0 = {0,0,0,0}, acc1 = {0,0,0,0}, acc2 = {0,0,0,0}, acc3 = {0,0,0,0};
#pragma unroll
      for (int kk = 0; kk < 4; ++kk) {
        bf16x8 a = *(const bf16x8*)&X_lds[l15][kk * 32 + kbase];
        bf16x8 e0 = *(const bf16x8*)&E_lds[nsub +      l15][kk * 32 + kbase];
        bf16x8 e1 = *(const bf16x8*)&E_lds[nsub + 16 + l15][kk * 32 + kbase];
        bf16x8 e2 = *(const bf16x8*)&E_lds[nsub + 32 + l15][kk * 32 + kbase];
        bf16x8 e3 = *(const bf16x8*)&E_lds[nsub + 48 + l15][kk * 32 + kbase];
        acc0 = __builtin_amdgcn_mfma_f32_16x16x32_bf16(a, e0, acc0, 0, 0, 0);
        acc1 = __builtin_amdgcn_mfma_f32_16x16x32_bf16(a, e1, acc1, 0, 0, 0);
        acc2 = __builtin_amdgcn_mfma_f32_16x16x32_bf16(a, e2, acc2, 0, 0, 0);
        acc3 = __builtin_amdgcn_mfma_f32_16x16x32_bf16(a, e3, acc3, 0, 0, 0);
      }

      // ---- wait for s_t ----
      if (t > 0) {
        unsigned tgt = 8u * (unsigned)t, guard = 0;
        if constexpr (FAST) {
          while (loadU32_l2(ctr) < tgt) {
            __builtin_amdgcn_s_sleep(1);
            if (++guard > 400000u) break;
          }
        } else {
          while (__hip_atomic_load(ctr, __ATOMIC_RELAXED, __HIP_MEMORY_SCOPE_AGENT) < tgt) {
            __builtin_amdgcn_s_sleep(1);
            if (++guard > 100000u) break;
          }
        }
      }
      // ---- stage s-half: S f32 -> bf16 LDS (one coalesced pass) ----
      {
        const float* Sr = Sbuf + (t & 3) * (CB * DST);
        int row = tid >> 4, c8 = tid & 15;
        const float* p = Sr + (size_t)(b0 + row) * DST + c8 * 8;
        short s8[8];
        if constexpr (FAST) {
          f32x4 va, vb;
          asm volatile("global_load_dwordx4 %0, %2, off sc0\n\t"
                       "global_load_dwordx4 %1, %2, off offset:16 sc0\n\t"
                       "s_waitcnt vmcnt(0)"
                       : "=&v"(va), "=&v"(vb) : "v"(p) : "memory");
          s8[0]=f2b(va[0]); s8[1]=f2b(va[1]); s8[2]=f2b(va[2]); s8[3]=f2b(va[3]);
          s8[4]=f2b(vb[0]); s8[5]=f2b(vb[1]); s8[6]=f2b(vb[2]); s8[7]=f2b(vb[3]);
        } else {
          const unsigned long long* q = (const unsigned long long*)p;
#pragma unroll
          for (int z = 0; z < 4; ++z) {
            unsigned long long w = __hip_atomic_load(q + z, __ATOMIC_RELAXED,
                                                     __HIP_MEMORY_SCOPE_AGENT);
            s8[2 * z]     = f2b(__builtin_bit_cast(float, (unsigned)(w & 0xffffffffu)));
            s8[2 * z + 1] = f2b(__builtin_bit_cast(float, (unsigned)(w >> 32)));
          }
        }
        *(short4*)&X_lds[row][DIN + c8 * 8]     = make_short4(s8[0], s8[1], s8[2], s8[3]);
        *(short4*)&X_lds[row][DIN + c8 * 8 + 4] = make_short4(s8[4], s8[5], s8[6], s8[7]);
      }
      __syncthreads();   // (1) s-half visible

      // ---- GEMM A s-half (kk 4..7) ----
#pragma unroll
      for (int kk = 4; kk < 8; ++kk) {
        bf16x8 a = *(const bf16x8*)&X_lds[l15][kk * 32 + kbase];
        bf16x8 e0 = *(const bf16x8*)&E_lds[nsub +      l15][kk * 32 + kbase];
        bf16x8 e1 = *(const bf16x8*)&E_lds[nsub + 16 + l15][kk * 32 + kbase];
        bf16x8 e2 = *(const bf16x8*)&E_lds[nsub + 32 + l15][kk * 32 + kbase];
        bf16x8 e3 = *(const bf16x8*)&E_lds[nsub + 48 + l15][kk * 32 + kbase];
        acc0 = __builtin_amdgcn_mfma_f32_16x16x32_bf16(a, e0, acc0, 0, 0, 0);
        acc1 = __builtin_amdgcn_mfma_f32_16x16x32_bf16(a, e1, acc1, 0, 0, 0);
        acc2 = __builtin_amdgcn_mfma_f32_16x16x32_bf16(a, e2, acc2, 0, 0, 0);
        acc3 = __builtin_amdgcn_mfma_f32_16x16x32_bf16(a, e3, acc3, 0, 0, 0);
      }
      {   // epilogue: relu(gain*x + bias) -> bf16 a-tile
        const int nc0 = nsub + l15, nc1 = nc0 + 16, nc2 = nc0 + 32, nc3 = nc0 + 48;
        const float g0 = gain_lds[nc0], bi0 = bias_lds[nc0];
        const float g1 = gain_lds[nc1], bi1 = bias_lds[nc1];
        const float g2 = gain_lds[nc2], bi2 = bias_lds[nc2];
        const float g3 = gain_lds[nc3], bi3 = bias_lds[nc3];
#pragma unroll
        for (int j = 0; j < 4; ++j) {
          A_lds[lhi * 4 + j][nc0] = f2b(fmaxf(g0 * acc0[j] + bi0, 0.f));
          A_lds[lhi * 4 + j][nc1] = f2b(fmaxf(g1 * acc1[j] + bi1, 0.f));
          A_lds[lhi * 4 + j][nc2] = f2b(fmaxf(g2 * acc2[j] + bi2, 0.f));
          A_lds[lhi * 4 + j][nc3] = f2b(fmaxf(g3 * acc3[j] + bi3, 0.f));
        }
      }
      __syncthreads();   // (2) A_lds ready; X free

      if (t != CT - 1) {
        // ---- GEMM B: (16x256)@(256x128); B-operand in registers ----
        f32x4 p0 = {0,0,0,0}, p1 = {0,0,0,0};
#pragma unroll
        for (int kk = 0; kk < 8; ++kk) {
          bf16x8 a = *(const bf16x8*)&A_lds[l15][kk * 32 + kbase];
          p0 = __builtin_amdgcn_mfma_f32_16x16x32_bf16(a, sdt0[kk], p0, 0, 0, 0);
          p1 = __builtin_amdgcn_mfma_f32_16x16x32_bf16(a, sdt1[kk], p1, 0, 0, 0);
        }
        // ---- f32 RMWs into S[(t+1)&3] ----
        float* Sw = Sbuf + ((t + 1) & 3) * (CB * DST);
        const int dA = wave * 32 + l15, dB = dA + 16;
#pragma unroll
        for (int j = 0; j < 4; ++j) {
          float* pA = &Sw[(size_t)(b0 + lhi * 4 + j) * DST + dA];
          float* pB = &Sw[(size_t)(b0 + lhi * 4 + j) * DST + dB];
          if constexpr (FAST) { addF32_l2(pA, p0[j]); addF32_l2(pB, p1[j]); }
          else { unsafeAtomicAdd(pA, p0[j]); unsafeAtomicAdd(pB, p1[j]); }
        }
        // ---- stage u_{t+1} into X (overlaps the add drain) ----
#pragma unroll
        for (int i = 0; i < 2; ++i) {
          int fidx = i * 256 + tid;
          int row = fidx >> 5, c4 = fidx & 31;
          *(short4*)&X_lds[row][c4 << 2] = f2b4(pu[i]);
        }
        __syncthreads();   // (3) drains adds + zero-stores + u-stage
        if (tid == 0) {
          if constexpr (FAST) addU32_l2(ctr, 1u);
          else atomicAdd(ctr, 1u);
        }
        // ---- off-path: u_{t+2} prefetch ----
        if (t + 2 < CT) {
#pragma unroll
          for (int i = 0; i < 2; ++i) {
            int fidx = i * 256 + tid;
            int row = fidx >> 5, c4 = fidx & 31;
            pu[i] = *(const float4*)(seq + ((size_t)(b0 + row) * CT + (t + 2)) * DIN + (c4 << 2));
          }
        }
      } else {
        // ---- final step: out partial = a_final @ decoders[n0:n0+256] ----
        f32x4 o0 = {0,0,0,0};
        const int ocol = wave * 16 + l15;
#pragma unroll
        for (int kk = 0; kk < 8; ++kk) {
          bf16x8 a = *(const bf16x8*)&A_lds[l15][kk * 32 + kbase];
          bf16x8 bfD;
#pragma unroll
          for (int j = 0; j < 8; ++j)
            bfD[j] = f2b(dec[(size_t)(n0 + kk * 32 + kbase + j) * DOUT + ocol]);
          o0 = __builtin_amdgcn_mfma_f32_16x16x32_bf16(a, bfD, o0, 0, 0, 0);
        }
#pragma unroll
        for (int j = 0; j < 4; ++j)       // cross-XCD-safe: agent scope
          unsafeAtomicAdd(&out[(size_t)(b0 + lhi * 4 + j) * DOUT + ocol], o0[j]);
      }
    }
  };

  if (fast) body(BoolC<true>{});
  else      body(BoolC<false>{});
}

extern "C" void kernel_launch(void* const* d_in, const int* in_sizes, int n_in,
                              void* d_out, int out_size, void* d_ws, size_t ws_size,
                              hipStream_t stream) {
  const float* seq   = (const float*)d_in[0];
  const float* enc   = (const float*)d_in[1];
  const float* gainp = (const float*)d_in[2];
  const float* biasp = (const float*)d_in[3];
  const float* sdec  = (const float*)d_in[4];
  const float* dec   = (const float*)d_in[5];
  float* out = (float*)d_out;

  // workspace: Sbuf 512 KB | ctrs 4 KB | xtab 512 B
  float* Sbuf = (float*)d_ws;
  unsigned int* ctrs = (unsigned int*)((char*)d_ws + (size_t)4 * CB * DST * sizeof(float));
  unsigned int* xtab = ctrs + 16 * 64;

  nef_init<<<128, 256, 0, stream>>>(Sbuf, ctrs, xtab, out);
  nef_main<<<dim3(NBG * NNG), dim3(256), 0, stream>>>(seq, enc, gainp, biasp,
                                                      sdec, dec, out, Sbuf, ctrs, xtab);
}

// Round 18
// 1477.002 us; speedup vs baseline: 2831.3999x; 2831.3999x over previous
//
#include <hip/hip_runtime.h>

// RecurrentNEFLayer on MI355X — persistent-kernel scan.
// r18 = resubmission of the r11 champion (1505us, absmax 0.015625).
// Rounds 15-17 were infra failures (dead container) — the kernel never ran.
// 128 blocks = 16 batch-groups (16 rows) x 8 neuron-groups (256 neurons).
// Encoders (256x256) LDS-resident bf16; state_decoders in REGISTERS.
// Fence-free memory-side protocol: unsafeAtomicAdd f32 (MALL RMW reduction),
// one block-flag RMW per step, relaxed agent atomic loads/stores for all
// cross-block data, 4-buffer S rotation with distributed zeroing.

constexpr int CB   = 256;   // batch
constexpr int CT   = 512;   // time steps
constexpr int DIN  = 128;
constexpr int DST  = 128;
constexpr int DOUT = 64;
constexpr int DAUG = 256;   // DIN + DST

constexpr int NBG = 16;     // batch groups
constexpr int NNG = 8;      // neuron groups (blocks per barrier group)
constexpr int BT  = 16;     // batch rows per group
constexpr int NT  = 256;    // neurons per block

constexpr int EPAD = 264;   // 256 + 8 bf16 pad
constexpr int APAD = 264;   // 256 + 8 bf16 pad (A is [b][n], n=256)

using f32x4  = __attribute__((ext_vector_type(4))) float;
using bf16x8 = __attribute__((ext_vector_type(8))) short;   // 8 bf16 in 4 VGPRs

__device__ __forceinline__ short f2b(float x) {   // f32 -> bf16 RNE
  unsigned u = __builtin_bit_cast(unsigned, x);
  u += 0x7fffu + ((u >> 16) & 1u);
  return (short)(u >> 16);
}
__device__ __forceinline__ short4 f2b4(float4 v) {
  return make_short4(f2b(v.x), f2b(v.y), f2b(v.z), f2b(v.w));
}

__global__ void nef_init(float* Sbuf, unsigned int* ctrs, float* out) {
  int idx = blockIdx.x * blockDim.x + threadIdx.x;
  int stride = gridDim.x * blockDim.x;
  for (int i = idx; i < 4 * CB * DST; i += stride) Sbuf[i] = 0.f;  // 4 state buffers
  for (int i = idx; i < CB * DOUT; i += stride) out[i] = 0.f;
  if (idx < 16 * 64) ctrs[idx] = 0u;                               // barrier ctrs
}

__global__ void __launch_bounds__(256) nef_main(
    const float* __restrict__ seq,  const float* __restrict__ enc,
    const float* __restrict__ gainp,const float* __restrict__ biasp,
    const float* __restrict__ sdec, const float* __restrict__ dec,
    float* __restrict__ out, float* __restrict__ Sbuf, unsigned int* ctrs)
{
  __shared__ short E_lds[NT][EPAD];     // encoders tile  [n][k_aug]   135.2 KB
  __shared__ short X_lds[BT][EPAD];     // [u_t | s_t]    [b][k_aug]     8.4 KB
  __shared__ short A_lds[BT][APAD];     // activations    [b][n]         8.4 KB
  __shared__ float gain_lds[NT];
  __shared__ float bias_lds[NT];

  const int tid  = threadIdx.x;
  const int bg   = blockIdx.x & 15;   // group's 8 blocks spread over XCDs (perf only)
  const int ng   = blockIdx.x >> 4;
  const int b0   = bg * BT;
  const int n0   = ng * NT;
  const int wave = tid >> 6;
  const int lane = tid & 63;
  const int l15  = lane & 15;
  const int lhi  = lane >> 4;         // 0..3
  const int kbase = lhi * 8;

  // ---- one-time: stage encoders into LDS (bf16): 256 rows x 256 cols f32 ----
  for (int i = 0; i < 64; ++i) {
    int fidx = i * 256 + tid;
    int row = fidx >> 6, c4 = fidx & 63;
    const float4 v = *(const float4*)(enc + (size_t)(n0 + row) * DAUG + (c4 << 2));
    *(short4*)&E_lds[row][c4 << 2] = f2b4(v);
  }
  gain_lds[tid] = gainp[n0 + tid];    // NT == blockDim == 256
  bias_lds[tid] = biasp[n0 + tid];

  // ---- one-time: gather state_decoders^T fragments into REGISTERS ----
  // GEMM B B-operand: wave w covers d-cols w*32+{0..15} (frag0) and +16 (frag1),
  // K = this block's 256 neurons in 8 chunks of 32.
  bf16x8 sdt0[8], sdt1[8];
#pragma unroll
  for (int kk = 0; kk < 8; ++kk) {
    bf16x8 f0, f1;
    const int dA = wave * 32 + l15, dB = dA + 16;
#pragma unroll
    for (int j = 0; j < 8; ++j) {
      const size_t nrow = (size_t)(n0 + kk * 32 + kbase + j) * DST;
      f0[j] = f2b(sdec[nrow + dA]);
      f1[j] = f2b(sdec[nrow + dB]);
    }
    sdt0[kk] = f0; sdt1[kk] = f1;
  }

  unsigned int* ctr = ctrs + bg * 64;   // one 256B-strided ctr per group
  const int nsub = wave * 64;           // wave's 64-neuron range in GEMM A

  // ---- prologue: load u_0, stage X u-half, prefetch u_1 ----
  float4 pu[2];
#pragma unroll
  for (int i = 0; i < 2; ++i) {
    int fidx = i * 256 + tid;
    int row = fidx >> 5, c4 = fidx & 31;
    pu[i] = *(const float4*)(seq + ((size_t)(b0 + row) * CT + 0) * DIN + (c4 << 2));
  }
#pragma unroll
  for (int i = 0; i < 2; ++i) {
    int fidx = i * 256 + tid;
    int row = fidx >> 5, c4 = fidx & 31;
    *(short4*)&X_lds[row][c4 << 2] = f2b4(pu[i]);
    pu[i] = *(const float4*)(seq + ((size_t)(b0 + row) * CT + 1) * DIN + (c4 << 2));
  }
  __syncthreads();   // weights + u_0 staged

  for (int t = 0; t < CT; ++t) {
    // ---- zero S[(t+2)&3] (fire-forget agent stores; drained by barrier (3)
    // below, before this step's flag). Readers of that buffer ran at t-2 (we
    // passed poll(t-1)); its next adders run at t+1 after our flag(t). ----
    {
      float* Sz = Sbuf + ((t + 2) & 3) * (CB * DST);
      __hip_atomic_store(&Sz[b0 * DST + ng * 256 + tid], 0.f,
                         __ATOMIC_RELAXED, __HIP_MEMORY_SCOPE_AGENT);
    }

    // ---- GEMM A u-half (kk 0..3): s-independent pre-poll work ----
    f32x4 acc0 = {0,0,0,0}, acc1 = {0,0,0,0}, acc2 = {0,0,0,0}, acc3 = {0,0,0,0};
#pragma unroll
    for (int kk = 0; kk < 4; ++kk) {
      bf16x8 a = *(const bf16x8*)&X_lds[l15][kk * 32 + kbase];
      bf16x8 e0 = *(const bf16x8*)&E_lds[nsub +      l15][kk * 32 + kbase];
      bf16x8 e1 = *(const bf16x8*)&E_lds[nsub + 16 + l15][kk * 32 + kbase];
      bf16x8 e2 = *(const bf16x8*)&E_lds[nsub + 32 + l15][kk * 32 + kbase];
      bf16x8 e3 = *(const bf16x8*)&E_lds[nsub + 48 + l15][kk * 32 + kbase];
      acc0 = __builtin_amdgcn_mfma_f32_16x16x32_bf16(a, e0, acc0, 0, 0, 0);
      acc1 = __builtin_amdgcn_mfma_f32_16x16x32_bf16(a, e1, acc1, 0, 0, 0);
      acc2 = __builtin_amdgcn_mfma_f32_16x16x32_bf16(a, e2, acc2, 0, 0, 0);
      acc3 = __builtin_amdgcn_mfma_f32_16x16x32_bf16(a, e3, acc3, 0, 0, 0);
    }

    // ---- wait for s_t: all 8 group blocks posted step t-1 adds ----
    if (t > 0) {
      unsigned int tgt = 8u * (unsigned)t, guard = 0;
      while (__hip_atomic_load(ctr, __ATOMIC_RELAXED, __HIP_MEMORY_SCOPE_AGENT) < tgt) {
        __builtin_amdgcn_s_sleep(1);
        if (++guard > 100000u) break;   // bounded: wrong answer, never a wedge
      }
    }
    // ---- stage s-half: S f32 (coherent MALL) -> bf16 LDS, 8B agent loads ----
    {
      const float* Sr = Sbuf + (t & 3) * (CB * DST);
      int row = tid >> 4, c8 = tid & 15;       // 16 rows x 16 chunks of 8 f32
      const unsigned long long* p =
          (const unsigned long long*)(Sr + (size_t)(b0 + row) * DST + c8 * 8);
      short s8[8];
#pragma unroll
      for (int q = 0; q < 4; ++q) {
        unsigned long long w = __hip_atomic_load(p + q, __ATOMIC_RELAXED,
                                                 __HIP_MEMORY_SCOPE_AGENT);
        s8[2 * q]     = f2b(__builtin_bit_cast(float, (unsigned)(w & 0xffffffffu)));
        s8[2 * q + 1] = f2b(__builtin_bit_cast(float, (unsigned)(w >> 32)));
      }
      *(short4*)&X_lds[row][DIN + c8 * 8]     = make_short4(s8[0], s8[1], s8[2], s8[3]);
      *(short4*)&X_lds[row][DIN + c8 * 8 + 4] = make_short4(s8[4], s8[5], s8[6], s8[7]);
    }
    __syncthreads();   // (1) s-half of X visible

    // ---- GEMM A s-half (kk 4..7) ----
#pragma unroll
    for (int kk = 4; kk < 8; ++kk) {
      bf16x8 a = *(const bf16x8*)&X_lds[l15][kk * 32 + kbase];
      bf16x8 e0 = *(const bf16x8*)&E_lds[nsub +      l15][kk * 32 + kbase];
      bf16x8 e1 = *(const bf16x8*)&E_lds[nsub + 16 + l15][kk * 32 + kbase];
      bf16x8 e2 = *(const bf16x8*)&E_lds[nsub + 32 + l15][kk * 32 + kbase];
      bf16x8 e3 = *(const bf16x8*)&E_lds[nsub + 48 + l15][kk * 32 + kbase];
      acc0 = __builtin_amdgcn_mfma_f32_16x16x32_bf16(a, e0, acc0, 0, 0, 0);
      acc1 = __builtin_amdgcn_mfma_f32_16x16x32_bf16(a, e1, acc1, 0, 0, 0);
      acc2 = __builtin_amdgcn_mfma_f32_16x16x32_bf16(a, e2, acc2, 0, 0, 0);
      acc3 = __builtin_amdgcn_mfma_f32_16x16x32_bf16(a, e3, acc3, 0, 0, 0);
    }
    {   // epilogue: relu(gain*x + bias) -> bf16 a-tile in LDS
      const int nc0 = nsub + l15, nc1 = nc0 + 16, nc2 = nc0 + 32, nc3 = nc0 + 48;
      const float g0 = gain_lds[nc0], bi0 = bias_lds[nc0];
      const float g1 = gain_lds[nc1], bi1 = bias_lds[nc1];
      const float g2 = gain_lds[nc2], bi2 = bias_lds[nc2];
      const float g3 = gain_lds[nc3], bi3 = bias_lds[nc3];
#pragma unroll
      for (int j = 0; j < 4; ++j) {   // C/D: col=lane&15, row=(lane>>4)*4+j
        A_lds[lhi * 4 + j][nc0] = f2b(fmaxf(g0 * acc0[j] + bi0, 0.f));
        A_lds[lhi * 4 + j][nc1] = f2b(fmaxf(g1 * acc1[j] + bi1, 0.f));
        A_lds[lhi * 4 + j][nc2] = f2b(fmaxf(g2 * acc2[j] + bi2, 0.f));
        A_lds[lhi * 4 + j][nc3] = f2b(fmaxf(g3 * acc3[j] + bi3, 0.f));
      }
    }
    __syncthreads();   // (2) A_lds ready; X free to overwrite

    if (t != CT - 1) {
      // ---- GEMM B: (16 x 256) @ (256 x 128) -> partial s_{t+1};
      //      B-operand from registers (sdt0/sdt1) ----
      f32x4 p0 = {0,0,0,0}, p1 = {0,0,0,0};
#pragma unroll
      for (int kk = 0; kk < 8; ++kk) {
        bf16x8 a = *(const bf16x8*)&A_lds[l15][kk * 32 + kbase];
        p0 = __builtin_amdgcn_mfma_f32_16x16x32_bf16(a, sdt0[kk], p0, 0, 0, 0);
        p1 = __builtin_amdgcn_mfma_f32_16x16x32_bf16(a, sdt1[kk], p1, 0, 0, 0);
      }
      // ---- memory-side f32 RMWs into S[(t+1)&3]: 8 per thread ----
      float* Sw = Sbuf + ((t + 1) & 3) * (CB * DST);
      const int dA = wave * 32 + l15, dB = dA + 16;
#pragma unroll
      for (int j = 0; j < 4; ++j) {
        unsafeAtomicAdd(&Sw[(size_t)(b0 + lhi * 4 + j) * DST + dA], p0[j]);
        unsafeAtomicAdd(&Sw[(size_t)(b0 + lhi * 4 + j) * DST + dB], p1[j]);
      }
      // ---- stage u_{t+1} into X u-half (LDS work overlaps the add drain) ----
#pragma unroll
      for (int i = 0; i < 2; ++i) {
        int fidx = i * 256 + tid;
        int row = fidx >> 5, c4 = fidx & 31;
        *(short4*)&X_lds[row][c4 << 2] = f2b4(pu[i]);
      }
      __syncthreads();   // (3) drains adds + zero-stores (vmcnt) + u-stage LDS
      if (tid == 0) atomicAdd(ctr, 1u);
      // ---- off-path: issue u_{t+2} prefetch ----
      if (t + 2 < CT) {
#pragma unroll
        for (int i = 0; i < 2; ++i) {
          int fidx = i * 256 + tid;
          int row = fidx >> 5, c4 = fidx & 31;
          pu[i] = *(const float4*)(seq + ((size_t)(b0 + row) * CT + (t + 2)) * DIN + (c4 << 2));
        }
      }
    } else {
      // ---- final step: out partial = a_final @ decoders[n0:n0+256] ----
      f32x4 o0 = {0,0,0,0};
      const int ocol = wave * 16 + l15;   // 4 waves x 16 = DOUT
#pragma unroll
      for (int kk = 0; kk < 8; ++kk) {
        bf16x8 a = *(const bf16x8*)&A_lds[l15][kk * 32 + kbase];
        bf16x8 bfD;
#pragma unroll
        for (int j = 0; j < 8; ++j)
          bfD[j] = f2b(dec[(size_t)(n0 + kk * 32 + kbase + j) * DOUT + ocol]);
        o0 = __builtin_amdgcn_mfma_f32_16x16x32_bf16(a, bfD, o0, 0, 0, 0);
      }
#pragma unroll
      for (int j = 0; j < 4; ++j)         // one-time 8-way K-split reduction
        unsafeAtomicAdd(&out[(size_t)(b0 + lhi * 4 + j) * DOUT + ocol], o0[j]);
    }
  }
}

extern "C" void kernel_launch(void* const* d_in, const int* in_sizes, int n_in,
                              void* d_out, int out_size, void* d_ws, size_t ws_size,
                              hipStream_t stream) {
  const float* seq   = (const float*)d_in[0];
  const float* enc   = (const float*)d_in[1];
  const float* gainp = (const float*)d_in[2];
  const float* biasp = (const float*)d_in[3];
  const float* sdec  = (const float*)d_in[4];
  const float* dec   = (const float*)d_in[5];
  float* out = (float*)d_out;

  // workspace: Sbuf f32 [4][256][128] = 512 KB | ctrs 16*64 u32 = 4 KB
  float* Sbuf = (float*)d_ws;
  unsigned int* ctrs = (unsigned int*)((char*)d_ws + (size_t)4 * CB * DST * sizeof(float));

  nef_init<<<128, 256, 0, stream>>>(Sbuf, ctrs, out);
  nef_main<<<dim3(NBG * NNG), dim3(256), 0, stream>>>(seq, enc, gainp, biasp,
                                                      sdec, dec, out, Sbuf, ctrs);
}